// Round 16
// baseline (257.245 us; speedup 1.0000x reference)
//
#include <hip/hip_runtime.h>
#include <hip/hip_bf16.h>
#include <math.h>

#define TSTEPS 128
#define HD 16      // GRU hidden
#define G3 48      // 3*H gates
#define AD 32      // 2*H attention dim
#define CHUNK 8    // serial steps per gx-MFMA chunk
#define NCHK 16
#define RROW 18    // ring row halfs (16 + 2 pad)
#define RING_PW2 (2 * 3 * CHUNK * RROW)  // 864 halfs per wave (2 seq-dirs)
#define H1W 36     // K2 LDS row width in halfs
#define SEQ_HALFS 4096                   // per-seq history: 16c * 32u * 8

#define SC1 1.44269504088896340736f   // log2(e)   : sigmoid prescale
#define SC2 2.88539008177792681472f   // 2*log2(e) : tanh prescale

typedef _Float16 h2 __attribute__((ext_vector_type(2)));
typedef _Float16 h4 __attribute__((ext_vector_type(4)));
typedef _Float16 f16x8 __attribute__((ext_vector_type(8)));
typedef float f32x4 __attribute__((ext_vector_type(4)));
typedef unsigned int uint2v __attribute__((ext_vector_type(2)));

#if defined(__has_builtin)
#  if __has_builtin(__builtin_amdgcn_exp2f)
#    define EXP2F(x) __builtin_amdgcn_exp2f(x)
#  endif
#  if __has_builtin(__builtin_amdgcn_rcpf)
#    define RCPF(x) __builtin_amdgcn_rcpf(x)
#  endif
#  if __has_builtin(__builtin_amdgcn_permlane16_swap)
#    define HAS_PL16 1
#  endif
#endif
#ifndef EXP2F
#  define EXP2F(x) exp2f(x)
#endif
#ifndef RCPF
#  define RCPF(x) (1.0f / (x))
#endif

__device__ __forceinline__ float fdot2(h2 a, h2 b, float c) {
    return __builtin_amdgcn_fdot2(a, b, c, false);
}
// tanh(x) with pre-scaled input u = 2*log2e*x
__device__ __forceinline__ float tanh_pre(float u) {
    return 1.0f - 2.0f * RCPF(EXP2F(u) + 1.0f);
}
// sum of this lane's partial with its bit-4 partner (rows 0<->1, 2<->3).
// permlane16_swap(a,a): out0=[a0,a0,a2,a2], out1=[a1,a1,a3,a3] (16-lane rows)
// -> partner = (lane&16) ? out0 : out1.
__device__ __forceinline__ float half_combine(float part, int lane) {
#ifdef HAS_PL16
    const uint2v s = __builtin_amdgcn_permlane16_swap(
        __float_as_uint(part), __float_as_uint(part), false, false);
    const float other = (lane & 16) ? __uint_as_float(s[0]) : __uint_as_float(s[1]);
#else
    const float other = __shfl_xor(part, 16);
#endif
    return part + other;
}

// Guarded row-major MFMA fragment load (k = k0+e, 0 beyond D), scaled.
template<int D>
__device__ __forceinline__ f16x8 load_frag(const float* __restrict__ rowptr,
                                           int k0, float scale) {
    f16x8 f;
    #pragma unroll
    for (int e = 0; e < 8; ++e) {
        const int k = k0 + e;
        f[e] = (k < D) ? (_Float16)(rowptr[k] * scale) : (_Float16)0.0f;
    }
    return f;
}

// ---------------- K1: serial recurrence (2 seqs/block, 2 lanes/h-unit) ------
// 128 threads = 2 waves. wave0 = fwd, wave1 = bwd over the block's TWO seqs.
// Lane (q,p,u): seq q, dot-half p, h-unit u. Each lane computes half-dots for
// all three gates (12 fdot2); halves combine via permlane16_swap (VALU).
// gx = x @ Wih^T via MFMA per 8-step chunk into a per-wave LDS ring.
// History streamed to global identically to R15's layout (K2 unchanged).
template<int D>
__global__ __launch_bounds__(128, 8)
void gru_serial_kernel(
    const float* __restrict__ x,                      // [S, TSTEPS, D]
    const float* __restrict__ Wih_f, const float* __restrict__ Whh_f,
    const float* __restrict__ bih_f, const float* __restrict__ bhh_f,
    const float* __restrict__ Wih_b, const float* __restrict__ Whh_b,
    const float* __restrict__ bih_b, const float* __restrict__ bhh_b,
    _Float16* __restrict__ ghist)
{
    __shared__ __align__(16) _Float16 ring[2 * RING_PW2];   // 3456 B
    __shared__ __align__(16) _Float16 hx[8 * HD];           // 256 B (rows 4-7 dump)

    const int tid  = threadIdx.x;
    const int lane = tid & 63;
    const int wv   = tid >> 6;
    const int dir  = wv;                 // wave0 = fwd, wave1 = bwd
    const int u    = lane & 15;          // h-unit / fragment row/col
    const int p    = (lane >> 4) & 1;    // dot half
    const int q    = lane >> 5;          // seq index within block (0..1)
    const int kg   = (lane >> 4) & 3;    // fragment k group
    const int k0   = kg * 8;
    const int sd   = wv * 2 + q;         // block-local chain row (0..3)

    const float* WihP = dir ? Wih_b : Wih_f;
    const float* WhhP = dir ? Whh_b : Whh_f;
    const float* bihP = dir ? bih_b : bih_f;
    const float* bhhP = dir ? bhh_b : bhh_f;

    // half-row recurrent weights (prescaled): k = p*8 .. p*8+7
    h2 wr_[4], wz_[4], wn_[4];
    #pragma unroll
    for (int j = 0; j < 8; ++j) {
        wr_[j >> 1][j & 1] = (_Float16)(WhhP[u * HD + p * 8 + j] * SC1);
        wz_[j >> 1][j & 1] = (_Float16)(WhhP[(HD + u) * HD + p * 8 + j] * SC1);
        wn_[j >> 1][j & 1] = (_Float16)(WhhP[(2 * HD + u) * HD + p * 8 + j] * SC2);
    }
    // biases enter via the p==0 partial only (combine adds them once)
    const float brz0 = p ? 0.0f : (bihP[u] + bhhP[u]) * SC1;
    const float bzz0 = p ? 0.0f : (bihP[HD + u] + bhhP[HD + u]) * SC1;
    const float bhn0 = p ? 0.0f : bhhP[2 * HD + u] * SC2;
    const float bxn  = bihP[2 * HD + u] * SC2;

    // persistent B fragments (this wave's dir)
    f16x8 bfrag[3];
    #pragma unroll
    for (int n = 0; n < 3; ++n)
        bfrag[n] = load_frag<D>(WihP + (16 * n + u) * D, k0, n < 2 ? SC1 : SC2);

    // A-fragment source: row fr=u -> seq u>>3, step u&7
    const size_t xstride = (size_t)TSTEPS * D;
    const float* xrow0 = x + (size_t)(blockIdx.x * 2 + (u >> 3)) * xstride;
    const int lsA = u & 7;

    _Float16* ringw = ring + wv * RING_PW2;
    const _Float16* ringrd = ringw + (q * 3 * CHUNK) * RROW + u;
    _Float16* hxw = hx + (p ? (4 + sd) : sd) * HD + u;   // rows 4-7 = dump
    const _Float16* hxr = hx + sd * HD + p * 8;          // this lane's 16B half

    _Float16* ghp = ghist + (size_t)(blockIdx.x * 2 + q) * SEQ_HALFS
                    + (size_t)(dir ? (16 + u) : u) * 8
                    + (dir ? 15 * 256 : 0);
    const int cstep = dir ? -256 : 256;

    float h_own = 0.0f;
    f16x8 afrag = load_frag<D>(xrow0 + (size_t)(dir ? (TSTEPS - 1 - lsA) : lsA) * D,
                               k0, 1.0f);

    for (int c = 0; c < NCHK; ++c) {
        // gx via MFMA -> ring (C row r = kg*4+qi -> q=r>>3, ls=r&7)
        #pragma unroll
        for (int n = 0; n < 3; ++n) {
            f32x4 a0 = {0.f, 0.f, 0.f, 0.f};
            a0 = __builtin_amdgcn_mfma_f32_16x16x32_f16(afrag, bfrag[n], a0, 0, 0, 0);
            #pragma unroll
            for (int qi = 0; qi < 4; ++qi) {
                const int r = kg * 4 + qi;
                ringw[(((r >> 3) * 3 + n) * CHUNK + (r & 7)) * RROW + u] = (_Float16)a0[qi];
            }
        }
        // prefetch next chunk's A fragment (hidden under 8 serial steps)
        f16x8 afn;
        if (c + 1 < NCHK) {
            const int s0 = (c + 1) * CHUNK + lsA;
            afn = load_frag<D>(xrow0 + (size_t)(dir ? (TSTEPS - 1 - s0) : s0) * D,
                               k0, 1.0f);
        }

        f16x8 hpk;

        // serial 8 steps: half-dots + permlane combine, no DS in exchange
        #pragma unroll
        for (int ls = 0; ls < CHUNK; ++ls) {
            const float gxr = (float)ringrd[(0 * CHUNK + ls) * RROW];
            const float gxz = (float)ringrd[(1 * CHUNK + ls) * RROW];
            const float gxn = (float)ringrd[(2 * CHUNK + ls) * RROW] + bxn;

            float sr = brz0, sz = bzz0, sn = bhn0;
            float sr1 = 0.f, sz1 = 0.f, sn1 = 0.f;
            if (!(c == 0 && ls == 0)) {
                const f16x8 hv = *reinterpret_cast<const f16x8*>(hxr);
                sr  = fdot2(wr_[0], (h2){hv[0], hv[1]}, sr );
                sr1 = fdot2(wr_[1], (h2){hv[2], hv[3]}, sr1);
                sr  = fdot2(wr_[2], (h2){hv[4], hv[5]}, sr );
                sr1 = fdot2(wr_[3], (h2){hv[6], hv[7]}, sr1);
                sz  = fdot2(wz_[0], (h2){hv[0], hv[1]}, sz );
                sz1 = fdot2(wz_[1], (h2){hv[2], hv[3]}, sz1);
                sz  = fdot2(wz_[2], (h2){hv[4], hv[5]}, sz );
                sz1 = fdot2(wz_[3], (h2){hv[6], hv[7]}, sz1);
                sn  = fdot2(wn_[0], (h2){hv[0], hv[1]}, sn );
                sn1 = fdot2(wn_[1], (h2){hv[2], hv[3]}, sn1);
                sn  = fdot2(wn_[2], (h2){hv[4], hv[5]}, sn );
                sn1 = fdot2(wn_[3], (h2){hv[6], hv[7]}, sn1);
            }
            const float ghr = half_combine(sr + sr1, lane);
            const float ghz = half_combine(sz + sz1, lane);
            const float ghn = half_combine(sn + sn1, lane);

            const float r  = RCPF(1.0f + EXP2F(-(gxr + ghr)));
            const float zz = RCPF(1.0f + EXP2F(-(gxz + ghz)));
            const float nv = tanh_pre(gxn + r * ghn);
            const float hnew = nv + zz * (h_own - nv);
            h_own = hnew;
            const _Float16 hh16 = (_Float16)hnew;
            hxw[0] = hh16;               // p0 -> real row; p1 -> dump row
            hpk[ls] = hh16;
        }
        if (p == 0)
            *reinterpret_cast<f16x8*>(ghp + c * cstep) = hpk;   // coalesced 16B
        afrag = afn;
    }
}

// ---------------- K2: attention over the streamed history (unchanged) ------
template<bool HAS_PROJ>
__global__ __launch_bounds__(128, 4)
void attn_kernel(
    const _Float16* __restrict__ ghist,
    const float* __restrict__ Wa, const float* __restrict__ ba,
    const float* __restrict__ ctxv,
    const float* __restrict__ Wm, const float* __restrict__ bm,
    float* __restrict__ out, int out_cols)
{
    __shared__ __align__(16) _Float16 h1[TSTEPS * H1W];   // 9216 B
    __shared__ float w_sh[TSTEPS];
    __shared__ float red[4];
    __shared__ float cvp[4 * AD];

    const int tid  = threadIdx.x;
    const int lane = tid & 63;
    const int wave = tid >> 6;
    const int seq  = blockIdx.x;

    // stage ghist[seq] -> h1[t][u32]  (coalesced f16x8 loads)
    {
        const f16x8* src = reinterpret_cast<const f16x8*>(ghist + (size_t)seq * SEQ_HALFS);
        #pragma unroll
        for (int k = 0; k < 4; ++k) {
            const int idx = tid + k * 128;
            const f16x8 v = src[idx];
            const int u32 = idx & 31;
            const int tb  = (idx >> 5) * 8;
            const int flip = (u32 >= 16) ? 7 : 0;   // bwd chunks are s-ordered
            #pragma unroll
            for (int e = 0; e < 8; ++e)
                h1[(tb + (e ^ flip)) * H1W + u32] = v[e];
        }
    }
    __syncthreads();

    // tanh proj -> softmax over t
    {
        const int t = tid;
        float hh[AD];
        const h4* hr = reinterpret_cast<const h4*>(&h1[t * H1W]);
        #pragma unroll
        for (int pp = 0; pp < AD / 4; ++pp) {
            const h4 v = hr[pp];
            #pragma unroll
            for (int e = 0; e < 4; ++e) hh[4 * pp + e] = (float)v[e];
        }
        float st = 0.0f;
        for (int i = 0; i < AD; ++i) {
            float a0 = ba[i], a1 = 0.f;
            const float* war = &Wa[i * AD];
            #pragma unroll
            for (int k = 0; k < AD; k += 2) {
                a0 += war[k] * hh[k];
                a1 += war[k + 1] * hh[k + 1];
            }
            st += tanh_pre(SC2 * (a0 + a1)) * ctxv[i];
        }
        float m = st;
        #pragma unroll
        for (int off = 32; off > 0; off >>= 1) m = fmaxf(m, __shfl_xor(m, off));
        if (lane == 0) red[wave] = m;
        __syncthreads();
        m = fmaxf(red[0], red[1]);
        const float e = EXP2F(SC1 * (st - m));
        float ssum = e;
        #pragma unroll
        for (int off = 32; off > 0; off >>= 1) ssum += __shfl_xor(ssum, off);
        if (lane == 0) red[2 + wave] = ssum;
        __syncthreads();
        const float Z = red[2] + red[3];
        w_sh[tid] = e * RCPF(Z);
    }
    __syncthreads();

    // cv[i] = sum_t w[t] * h1[t][i]
    {
        const int g = tid >> 5, i = tid & 31;
        float acc = 0.0f;
        for (int k = 0; k < 32; ++k) {
            const int tt = g * 32 + k;
            acc += w_sh[tt] * (float)h1[tt * H1W + i];
        }
        cvp[g * AD + i] = acc;
    }
    __syncthreads();
    if (tid < AD)
        cvp[tid] = cvp[tid] + cvp[AD + tid] + cvp[2 * AD + tid] + cvp[3 * AD + tid];
    __syncthreads();

    if (HAS_PROJ) {
        if (tid < HD) {
            float acc = bm[tid];
            #pragma unroll
            for (int i = 0; i < AD; ++i) acc += Wm[tid * AD + i] * cvp[i];
            out[(size_t)seq * out_cols + tid] = acc;
        }
    } else {
        if (tid < AD) out[(size_t)seq * out_cols + tid] = cvp[tid];
    }
}

extern "C" void kernel_launch(void* const* d_in, const int* in_sizes, int n_in,
                              void* d_out, int out_size, void* d_ws, size_t ws_size,
                              hipStream_t stream) {
    const float* x     = (const float*)d_in[0];
    const float* Wih1f = (const float*)d_in[1];
    const float* Whh1f = (const float*)d_in[2];
    const float* bih1f = (const float*)d_in[3];
    const float* bhh1f = (const float*)d_in[4];
    const float* Wih1b = (const float*)d_in[5];
    const float* Whh1b = (const float*)d_in[6];
    const float* bih1b = (const float*)d_in[7];
    const float* bhh1b = (const float*)d_in[8];
    const float* Wih2f = (const float*)d_in[9];
    const float* Whh2f = (const float*)d_in[10];
    const float* bih2f = (const float*)d_in[11];
    const float* bhh2f = (const float*)d_in[12];
    const float* Wih2b = (const float*)d_in[13];
    const float* Whh2b = (const float*)d_in[14];
    const float* bih2b = (const float*)d_in[15];
    const float* bhh2b = (const float*)d_in[16];
    const float* Wa1   = (const float*)d_in[17];
    const float* ba1   = (const float*)d_in[18];
    const float* ctx1  = (const float*)d_in[19];
    const float* Wa2   = (const float*)d_in[20];
    const float* ba2   = (const float*)d_in[21];
    const float* ctx2  = (const float*)d_in[22];
    const float* Wm    = (const float*)d_in[23];
    const float* bm    = (const float*)d_in[24];

    float* flow = (float*)d_ws;                               // [8192,16] = 512KB
    const size_t histOff = 1u << 20;                          // 1 MB
    _Float16* ghist = (_Float16*)((char*)d_ws + histOff);     // 64 MB (reused by s2)
    float* outp = (float*)d_out;                              // [64, 32]

    // Stage 1: 8192 seqs, 2 per block -> history; then attention -> flow
    gru_serial_kernel<25><<<4096, 128, 0, stream>>>(
        x, Wih1f, Whh1f, bih1f, bhh1f, Wih1b, Whh1b, bih1b, bhh1b, ghist);
    attn_kernel<true><<<8192, 128, 0, stream>>>(
        ghist, Wa1, ba1, ctx1, Wm, bm, flow, 16);

    // Stage 2: 64 seqs (input = flow as [64,128,16]); ghist buffer reused
    gru_serial_kernel<16><<<32, 128, 0, stream>>>(
        flow, Wih2f, Whh2f, bih2f, bhh2f, Wih2b, Whh2b, bih2b, bhh2b, ghist);
    attn_kernel<false><<<64, 128, 0, stream>>>(
        ghist, Wa2, ba2, ctx2, nullptr, nullptr, outp, 32);
}